// Round 6
// baseline (672.601 us; speedup 1.0000x reference)
//
#include <hip/hip_runtime.h>
#include <math.h>

// SolarSpringAttention — split-bf16 MFMA GEMMs (global_load_lds + swizzle),
// fused decomposes, exact fp32 scores/softmax, nontemporal output stores.
// GEMM1 computes V^T = Wv · X^T so every GEMM operand and output is consumed
// and produced in natural row-major M×K / N×K layout (no scattered epilogues).
// Output: out (L*d) | A (L*L) | scores (L*L), all f32, concatenated.
//
// ROUND 5 NOTE: identical to round-4 source. Seven rounds of broker
// GPUAcquisitionTimeout = zero feedback so far; holding the audited,
// verified-structure kernel so the first successful bench yields a clean
// baseline + counters. The 8-phase 256² GEMM rewrite is gated on that bench.

typedef __attribute__((ext_vector_type(8))) short bf16x8;
typedef __attribute__((ext_vector_type(4))) float f32x4;

__constant__ float POS_W[8] = {0.95f, 0.9f, 0.85f, 0.5f, 0.4f, 0.2f, 0.15f, 0.05f};

__device__ __forceinline__ float sigmoidf(float x) { return 1.0f / (1.0f + expf(-x)); }

__device__ __forceinline__ unsigned short f2bf(float x) {
  unsigned int u = __float_as_uint(x);
  unsigned int r = (u + 0x7fffu + ((u >> 16) & 1u)) >> 16;  // RNE
  return (unsigned short)r;
}
__device__ __forceinline__ float bf2f(unsigned short h) {
  return __uint_as_float(((unsigned int)h) << 16);
}

// async 16B global -> LDS (wave-linear dest: lane l writes ldst + l*16 bytes)
__device__ __forceinline__ void load_lds16(const unsigned short* g, unsigned short* l) {
  __builtin_amdgcn_global_load_lds(
      (const __attribute__((address_space(1))) void*)g,
      (__attribute__((address_space(3))) void*)l, 16, 0, 0);
}

// ---------------- fused: decompose X + per-token precompute ----------------
__global__ __launch_bounds__(256) void fusedX_kernel(
    const float* __restrict__ tv, const int* __restrict__ pos_idx,
    const float* __restrict__ conf, const float* __restrict__ reso,
    const float* __restrict__ k_spring,
    unsigned short* __restrict__ Xh, unsigned short* __restrict__ Xl,
    float* __restrict__ masses, float* __restrict__ bh, float* __restrict__ kpis,
    int L, int d) {
  int i = blockIdx.x;
  int tid = threadIdx.x;
  const float* row = tv + (size_t)i * d;
  unsigned short* hrow = Xh + (size_t)i * d;
  unsigned short* lrow = Xl + (size_t)i * d;
  float s = 0.0f;
  for (int c = tid * 4; c < d; c += 1024) {
    float4 v = *(const float4*)(row + c);
    s = fmaf(v.x, v.x, fmaf(v.y, v.y, fmaf(v.z, v.z, fmaf(v.w, v.w, s))));
    ushort4 h, l;
    h.x = f2bf(v.x); l.x = f2bf(v.x - bf2f(h.x));
    h.y = f2bf(v.y); l.y = f2bf(v.y - bf2f(h.y));
    h.z = f2bf(v.z); l.z = f2bf(v.z - bf2f(h.z));
    h.w = f2bf(v.w); l.w = f2bf(v.w - bf2f(h.w));
    *(ushort4*)(hrow + c) = h;
    *(ushort4*)(lrow + c) = l;
  }
  for (int o = 32; o > 0; o >>= 1) s += __shfl_down(s, o);
  __shared__ float red[4];
  int wid = tid >> 6, lane = tid & 63;
  if (lane == 0) red[wid] = s;
  __syncthreads();
  if (tid == 0) {
    float total = red[0] + red[1] + red[2] + red[3];
    float norm = sqrtf(total);
    int p = pos_idx[i] & 7;
    masses[i] = norm * POS_W[p] * (1.0f + reso[i]);
    float c0 = conf[i];
    float gap = fmaxf(c0 - 0.1f, 1e-6f);
    float b = -0.01f / (gap * gap);
    if (c0 <= 0.1f) b = -1e6f;
    bh[i] = b;
    kpis[i] = sigmoidf(k_spring[p]);
  }
}

// ---------------- flat decompose (weights) ----------------
__global__ __launch_bounds__(256) void decompose_kernel(
    const float* __restrict__ src, unsigned short* __restrict__ hi,
    unsigned short* __restrict__ lo, int n) {
  int i = (blockIdx.x * 256 + threadIdx.x) * 4;
  if (i >= n) return;
  float4 v = *(const float4*)&src[i];
  ushort4 h, l;
  h.x = f2bf(v.x); l.x = f2bf(v.x - bf2f(h.x));
  h.y = f2bf(v.y); l.y = f2bf(v.y - bf2f(h.y));
  h.z = f2bf(v.z); l.z = f2bf(v.z - bf2f(h.z));
  h.w = f2bf(v.w); l.w = f2bf(v.w - bf2f(h.w));
  *(ushort4*)&hi[i] = h;
  *(ushort4*)&lo[i] = l;
}

// ---------------- scores + softmax + A-decompose (one row per block) --------
__global__ __launch_bounds__(256) void scores_softmax_kernel(
    const float* __restrict__ masses, const float* __restrict__ bh,
    const float* __restrict__ kpis,
    const int* __restrict__ pos_idx, const int* __restrict__ slot_idx,
    const int* __restrict__ depth, const float* __restrict__ token_pos,
    const float* __restrict__ conf, const float* __restrict__ G_micro,
    const float* __restrict__ G_macro, const float* __restrict__ temperature,
    float* __restrict__ scores, float* __restrict__ A,
    unsigned short* __restrict__ Ahd, unsigned short* __restrict__ Ald, int L) {
  int i = blockIdx.x;
  int tid = threadIdx.x;
  __shared__ float sig_g[64];
  __shared__ float red[4];
  extern __shared__ float srow[];  // L floats

  if (tid < 64) sig_g[tid] = sigmoidf(G_micro[tid]);

  float sigmac = sigmoidf(G_macro[0]);
  float T = fmaxf(fabsf(temperature[0]), 0.1f);
  float invT = 1.0f / T;

  float m_i = masses[i];
  float bh_i = bh[i];
  float kpi = kpis[i];
  int pi = pos_idx[i] & 7;
  float slot_i = (float)slot_idx[i];
  float depth_i = (float)depth[i];
  float pos_i = token_pos[i];
  bool collapsed_i = conf[i] <= 0.1f;
  __syncthreads();

  float lmax = -INFINITY;
  for (int j = tid; j < L; j += 256) {
    float sc;
    if (j == i) {
      sc = 0.0f;
    } else if (collapsed_i) {
      sc = -1e6f;
    } else {
      int pj = pos_idx[j] & 7;
      float mm = m_i * masses[j];
      float Gk = sig_g[pi * 8 + pj];
      float sd = fmaxf(fabsf(slot_i - (float)slot_idx[j]), 1.0f);
      float f_micro = (Gk * mm) / (sd * sd);
      float dd = fabsf(depth_i - (float)depth[j]) + 1.0f;
      float f_macro = (sigmac * mm) / (dd * dd);
      float f_spring = kpi * fabsf(pos_i - token_pos[j]);
      sc = f_micro + f_macro + f_spring + bh_i + bh[j];
    }
    srow[j] = sc;
    __builtin_nontemporal_store(sc, &scores[(size_t)i * L + j]);  // write-once
    lmax = fmaxf(lmax, sc);
  }
  for (int o = 32; o > 0; o >>= 1) lmax = fmaxf(lmax, __shfl_down(lmax, o));
  int wid = tid >> 6, lane = tid & 63;
  if (lane == 0) red[wid] = lmax;
  __syncthreads();
  float rowmax = fmaxf(fmaxf(red[0], red[1]), fmaxf(red[2], red[3]));
  __syncthreads();

  float lsum = 0.0f;
  for (int j = tid; j < L; j += 256) {
    float e = expf((srow[j] - rowmax) * invT);
    srow[j] = e;
    lsum += e;
  }
  for (int o = 32; o > 0; o >>= 1) lsum += __shfl_down(lsum, o);
  if (lane == 0) red[wid] = lsum;
  __syncthreads();
  float total = red[0] + red[1] + red[2] + red[3];
  float inv = 1.0f / total;

  for (int j = tid; j < L; j += 256) {
    float a = srow[j] * inv;
    size_t o = (size_t)i * L + j;
    __builtin_nontemporal_store(a, &A[o]);  // f32 A never re-read on device
    unsigned short h = f2bf(a);
    Ahd[o] = h;                             // re-read by GEMM2 -> keep cached
    Ald[o] = f2bf(a - bf2f(h));
  }
}

// ---------------- split-bf16 MFMA GEMM ----------------
// C[m][n] = sum_k (Ah+Al)[m][k] * (Bh+Bl)[n][k]  (3-product split)
// A: M x K row-major bf16 pair, B: N x K row-major bf16 pair.
// MODE 0: f32 C[m][n] + bias[n] (column bias), nontemporal.
// MODE 2: bf16 pair Oh/Ol[m][n] + optional bias[m] (row bias, nullptr ok).
#define GBM 128
#define GBN 128
#define GBK 32

template <int MODE>
__global__ __launch_bounds__(256, 2) void gemm_split_kernel(
    const unsigned short* __restrict__ Ah, const unsigned short* __restrict__ Al,
    const unsigned short* __restrict__ Bh, const unsigned short* __restrict__ Bl,
    const float* __restrict__ bias, float* __restrict__ C,
    unsigned short* __restrict__ Oh, unsigned short* __restrict__ Ol,
    int M, int N, int K) {
  // 4 linear LDS tiles [128][32] bf16 = 8KB each
  __shared__ unsigned short smem[4][GBM * GBK];
  int tid = threadIdx.x;
  int wave = tid >> 6, lane = tid & 63;
  int wm = wave >> 1, wn = wave & 1;
  int m0 = blockIdx.y * GBM, n0 = blockIdx.x * GBN;

  // ---- staging setup: each wave owns one buffer ----
  // LDS[row][granule q] <- G[row][granule q ^ ((row>>1)&3)]; same XOR on read.
  int lrow = lane >> 2;  // 0..15 row-within-16-row-chunk
  int q = lane & 3;      // 16B granule index within the 64B row
  int cs = (q ^ ((lrow >> 1) & 3)) * 8;  // swizzled source column (ushorts)
  const unsigned short* gsrc;
  unsigned short* ldst;
  if (wave == 0)      { gsrc = Ah + (size_t)m0 * K; ldst = &smem[0][0]; }
  else if (wave == 1) { gsrc = Al + (size_t)m0 * K; ldst = &smem[1][0]; }
  else if (wave == 2) { gsrc = Bh + (size_t)n0 * K; ldst = &smem[2][0]; }
  else                { gsrc = Bl + (size_t)n0 * K; ldst = &smem[3][0]; }
  const unsigned short* lane_g = gsrc + (size_t)lrow * K + cs;

  // ---- fragment read setup ----
  int fr = lane & 15, fg = lane >> 4;
  int rd_col = (fg ^ ((fr >> 1) & 3)) * 8;  // swizzled LDS read column (ushorts)

  f32x4 zero = {0.0f, 0.0f, 0.0f, 0.0f};
  f32x4 acc[4][4];
#pragma unroll
  for (int a = 0; a < 4; ++a)
#pragma unroll
    for (int b = 0; b < 4; ++b) acc[a][b] = zero;

  for (int k0 = 0; k0 < K; k0 += GBK) {
#pragma unroll
    for (int c = 0; c < 8; ++c) {
      load_lds16(lane_g + (size_t)c * 16 * K + k0, ldst + c * 512);
    }
    __syncthreads();

    bf16x8 a_h[4], a_l[4], b_h[4], b_l[4];
#pragma unroll
    for (int mt = 0; mt < 4; ++mt) {
      int row = wm * 64 + mt * 16 + fr;
      a_h[mt] = *(const bf16x8*)&smem[0][row * GBK + rd_col];
      a_l[mt] = *(const bf16x8*)&smem[1][row * GBK + rd_col];
    }
#pragma unroll
    for (int nt = 0; nt < 4; ++nt) {
      int row = wn * 64 + nt * 16 + fr;
      b_h[nt] = *(const bf16x8*)&smem[2][row * GBK + rd_col];
      b_l[nt] = *(const bf16x8*)&smem[3][row * GBK + rd_col];
    }
#pragma unroll
    for (int mt = 0; mt < 4; ++mt)
#pragma unroll
      for (int nt = 0; nt < 4; ++nt) {
        acc[mt][nt] = __builtin_amdgcn_mfma_f32_16x16x32_bf16(
            a_h[mt], b_h[nt], acc[mt][nt], 0, 0, 0);
        acc[mt][nt] = __builtin_amdgcn_mfma_f32_16x16x32_bf16(
            a_h[mt], b_l[nt], acc[mt][nt], 0, 0, 0);
        acc[mt][nt] = __builtin_amdgcn_mfma_f32_16x16x32_bf16(
            a_l[mt], b_h[nt], acc[mt][nt], 0, 0, 0);
      }
    __syncthreads();
  }

  // ---- epilogue ----
#pragma unroll
  for (int mt = 0; mt < 4; ++mt) {
#pragma unroll
    for (int nt = 0; nt < 4; ++nt) {
      int row0 = m0 + wm * 64 + mt * 16 + fg * 4;
      int col = n0 + wn * 64 + nt * 16 + fr;
      f32x4 v = acc[mt][nt];
      if (MODE == 0) {
        float bv = bias[col];
#pragma unroll
        for (int j = 0; j < 4; ++j)
          __builtin_nontemporal_store(v[j] + bv, &C[(size_t)(row0 + j) * N + col]);
      } else {
#pragma unroll
        for (int j = 0; j < 4; ++j) {
          float x = v[j] + (bias ? bias[row0 + j] : 0.0f);
          unsigned short h = f2bf(x);
          size_t o = (size_t)(row0 + j) * N + col;
          Oh[o] = h;
          Ol[o] = f2bf(x - bf2f(h));
        }
      }
    }
  }
}

extern "C" void kernel_launch(void* const* d_in, const int* in_sizes, int n_in,
                              void* d_out, int out_size, void* d_ws, size_t ws_size,
                              hipStream_t stream) {
  const float* token_vecs = (const float*)d_in[0];
  const int* pos_idx = (const int*)d_in[1];
  const int* depth = (const int*)d_in[2];
  const int* slot_idx = (const int*)d_in[3];
  const float* token_pos = (const float*)d_in[4];
  const float* conf = (const float*)d_in[5];
  const float* reso = (const float*)d_in[6];
  const float* G_micro = (const float*)d_in[7];
  const float* G_macro = (const float*)d_in[8];
  const float* k_spring = (const float*)d_in[9];
  const float* temperature = (const float*)d_in[10];
  const float* Wv_w = (const float*)d_in[11];
  const float* Wv_b = (const float*)d_in[12];
  const float* Wout_w = (const float*)d_in[13];
  const float* Wout_b = (const float*)d_in[14];

  const int L = in_sizes[1];   // 4096
  const int d = in_sizes[12];  // 2048

  float* out = (float*)d_out;             // L*d
  float* A = out + (size_t)L * d;         // L*L
  float* scores = A + (size_t)L * L;      // L*L

  // workspace layout (~136MB; every buffer fully written before read)
  float* masses = (float*)d_ws;                          // L
  float* bhv = masses + L;                               // L
  float* kpis = bhv + L;                                 // L
  unsigned short* Ahd = (unsigned short*)(kpis + L);     // L*L
  unsigned short* Ald = Ahd + (size_t)L * L;             // L*L
  unsigned short* VTh = Ald + (size_t)L * L;             // d*L (V^T)
  unsigned short* VTl = VTh + (size_t)d * L;             // d*L
  unsigned short* Wh = VTl + (size_t)d * L;              // d*d (Wv then Wout)
  unsigned short* Wl = Wh + (size_t)d * d;               // d*d
  unsigned short* Xh = Wl + (size_t)d * d;               // L*d (reused as AVh)
  unsigned short* Xl = Xh + (size_t)L * d;               // L*d (reused as AVl)
  unsigned short* AVh = Xh;
  unsigned short* AVl = Xl;

  // 1. decompose X + per-token precompute (one pass over X)
  fusedX_kernel<<<L, 256, 0, stream>>>(token_vecs, pos_idx, conf, reso, k_spring,
                                       Xh, Xl, masses, bhv, kpis, L, d);

  // 2. decompose Wv
  decompose_kernel<<<(d * d) / 1024, 256, 0, stream>>>(Wv_w, Wh, Wl, d * d);

  // 3. scores + softmax (writes scores, A, and A bf16 pair)
  scores_softmax_kernel<<<L, 256, L * sizeof(float), stream>>>(
      masses, bhv, kpis, pos_idx, slot_idx, depth, token_pos, conf, G_micro,
      G_macro, temperature, scores, A, Ahd, Ald, L);

  // 4. V^T = Wv · X^T + Wv_b[row]   (M=d, N=L, K=d; all natural layouts)
  {
    dim3 grid(L / GBN, d / GBM);
    gemm_split_kernel<2><<<grid, 256, 0, stream>>>(Wh, Wl, Xh, Xl, Wv_b,
                                                   nullptr, VTh, VTl, d, L, d);
  }

  // 5. decompose Wout (reuses Wh/Wl after GEMM1 consumed them)
  decompose_kernel<<<(d * d) / 1024, 256, 0, stream>>>(Wout_w, Wh, Wl, d * d);

  // 6. AV pair = (A @ V) decomposed   (M=L, N=d, K=L; B = V^T natural)
  {
    dim3 grid(d / GBN, L / GBM);
    gemm_split_kernel<2><<<grid, 256, 0, stream>>>(Ahd, Ald, VTh, VTl, nullptr,
                                                   nullptr, AVh, AVl, L, d, L);
  }

  // 7. out = AV @ Wout^T + Wout_b   (M=L, N=d, K=d)
  {
    dim3 grid(d / GBN, L / GBM);
    gemm_split_kernel<0><<<grid, 256, 0, stream>>>(AVh, AVl, Wh, Wl, Wout_b,
                                                   out, nullptr, nullptr, L, d, d);
  }
}

// Round 12
// 657.855 us; speedup vs baseline: 1.0224x; 1.0224x over previous
//
#include <hip/hip_runtime.h>
#include <math.h>

// SolarSpringAttention — counted-vmcnt pipelined bf16 MFMA GEMMs over a
// virtual K'=3K split-bf16 concat ([Ah|Ah|Al]·[Bh|Bl|Bh]), fused decomposes,
// exact fp32 scores/softmax, nontemporal output stores.
// GEMM tile 128x128x64, 256 thr / 4 waves, double-buffered 64KB LDS,
// 2 blocks/CU; per-wave 8 global_load_lds per K-tile with s_waitcnt vmcnt(8)
// (loads stay in flight across raw s_barriers — T3/T4 counted pipeline).
// Explicit s_waitcnt lgkmcnt(0) before the trailing barrier closes the
// ds_read-in-flight vs DMA-overwrite race regardless of MFMA placement.
// ROUND 12: identical to round-10/11 source (broker timeout; 5th audit clean,
// absmax=16 root-caused to fp32 summation order on ~1e8 bh rows — benign).
// Output: out (L*d) | A (L*L) | scores (L*L), all f32, concatenated.

typedef __attribute__((ext_vector_type(8))) short bf16x8;
typedef __attribute__((ext_vector_type(4))) float f32x4;

__constant__ float POS_W[8] = {0.95f, 0.9f, 0.85f, 0.5f, 0.4f, 0.2f, 0.15f, 0.05f};

__device__ __forceinline__ float sigmoidf(float x) { return 1.0f / (1.0f + expf(-x)); }

__device__ __forceinline__ unsigned short f2bf(float x) {
  unsigned int u = __float_as_uint(x);
  unsigned int r = (u + 0x7fffu + ((u >> 16) & 1u)) >> 16;  // RNE
  return (unsigned short)r;
}
__device__ __forceinline__ float bf2f(unsigned short h) {
  return __uint_as_float(((unsigned int)h) << 16);
}

// async 16B global -> LDS (wave-uniform dest base; lane l writes dest + l*16B)
__device__ __forceinline__ void load_lds16(const unsigned short* g, unsigned short* l) {
  __builtin_amdgcn_global_load_lds(
      (const __attribute__((address_space(1))) void*)g,
      (__attribute__((address_space(3))) void*)l, 16, 0, 0);
}

// ---------------- fused: decompose X + per-token precompute ----------------
__global__ __launch_bounds__(256) void fusedX_kernel(
    const float* __restrict__ tv, const int* __restrict__ pos_idx,
    const float* __restrict__ conf, const float* __restrict__ reso,
    const float* __restrict__ k_spring,
    unsigned short* __restrict__ Xh, unsigned short* __restrict__ Xl,
    float* __restrict__ masses, float* __restrict__ bh, float* __restrict__ kpis,
    int L, int d) {
  int i = blockIdx.x;
  int tid = threadIdx.x;
  const float* row = tv + (size_t)i * d;
  unsigned short* hrow = Xh + (size_t)i * d;
  unsigned short* lrow = Xl + (size_t)i * d;
  float s = 0.0f;
  for (int c = tid * 4; c < d; c += 1024) {
    float4 v = *(const float4*)(row + c);
    s = fmaf(v.x, v.x, fmaf(v.y, v.y, fmaf(v.z, v.z, fmaf(v.w, v.w, s))));
    ushort4 h, l;
    h.x = f2bf(v.x); l.x = f2bf(v.x - bf2f(h.x));
    h.y = f2bf(v.y); l.y = f2bf(v.y - bf2f(h.y));
    h.z = f2bf(v.z); l.z = f2bf(v.z - bf2f(h.z));
    h.w = f2bf(v.w); l.w = f2bf(v.w - bf2f(h.w));
    *(ushort4*)(hrow + c) = h;
    *(ushort4*)(lrow + c) = l;
  }
  for (int o = 32; o > 0; o >>= 1) s += __shfl_down(s, o);
  __shared__ float red[4];
  int wid = tid >> 6, lane = tid & 63;
  if (lane == 0) red[wid] = s;
  __syncthreads();
  if (tid == 0) {
    float total = red[0] + red[1] + red[2] + red[3];
    float norm = sqrtf(total);
    int p = pos_idx[i] & 7;
    masses[i] = norm * POS_W[p] * (1.0f + reso[i]);
    float c0 = conf[i];
    float gap = fmaxf(c0 - 0.1f, 1e-6f);
    float b = -0.01f / (gap * gap);
    if (c0 <= 0.1f) b = -1e6f;
    bh[i] = b;
    kpis[i] = sigmoidf(k_spring[p]);
  }
}

// ---------------- flat decompose (weights) ----------------
__global__ __launch_bounds__(256) void decompose_kernel(
    const float* __restrict__ src, unsigned short* __restrict__ hi,
    unsigned short* __restrict__ lo, int n) {
  int i = (blockIdx.x * 256 + threadIdx.x) * 4;
  if (i >= n) return;
  float4 v = *(const float4*)&src[i];
  ushort4 h, l;
  h.x = f2bf(v.x); l.x = f2bf(v.x - bf2f(h.x));
  h.y = f2bf(v.y); l.y = f2bf(v.y - bf2f(h.y));
  h.z = f2bf(v.z); l.z = f2bf(v.z - bf2f(h.z));
  h.w = f2bf(v.w); l.w = f2bf(v.w - bf2f(h.w));
  *(ushort4*)&hi[i] = h;
  *(ushort4*)&lo[i] = l;
}

// ---------------- scores + softmax + A-decompose (one row per block) --------
__global__ __launch_bounds__(256) void scores_softmax_kernel(
    const float* __restrict__ masses, const float* __restrict__ bh,
    const float* __restrict__ kpis,
    const int* __restrict__ pos_idx, const int* __restrict__ slot_idx,
    const int* __restrict__ depth, const float* __restrict__ token_pos,
    const float* __restrict__ conf, const float* __restrict__ G_micro,
    const float* __restrict__ G_macro, const float* __restrict__ temperature,
    float* __restrict__ scores, float* __restrict__ A,
    unsigned short* __restrict__ Ahd, unsigned short* __restrict__ Ald, int L) {
  int i = blockIdx.x;
  int tid = threadIdx.x;
  __shared__ float sig_g[64];
  __shared__ float red[4];
  extern __shared__ float srow[];  // L floats

  if (tid < 64) sig_g[tid] = sigmoidf(G_micro[tid]);

  float sigmac = sigmoidf(G_macro[0]);
  float T = fmaxf(fabsf(temperature[0]), 0.1f);
  float invT = 1.0f / T;

  float m_i = masses[i];
  float bh_i = bh[i];
  float kpi = kpis[i];
  int pi = pos_idx[i] & 7;
  float slot_i = (float)slot_idx[i];
  float depth_i = (float)depth[i];
  float pos_i = token_pos[i];
  bool collapsed_i = conf[i] <= 0.1f;
  __syncthreads();

  float lmax = -INFINITY;
  for (int j = tid; j < L; j += 256) {
    float sc;
    if (j == i) {
      sc = 0.0f;
    } else if (collapsed_i) {
      sc = -1e6f;
    } else {
      int pj = pos_idx[j] & 7;
      float mm = m_i * masses[j];
      float Gk = sig_g[pi * 8 + pj];
      float sd = fmaxf(fabsf(slot_i - (float)slot_idx[j]), 1.0f);
      float f_micro = (Gk * mm) / (sd * sd);
      float dd = fabsf(depth_i - (float)depth[j]) + 1.0f;
      float f_macro = (sigmac * mm) / (dd * dd);
      float f_spring = kpi * fabsf(pos_i - token_pos[j]);
      sc = f_micro + f_macro + f_spring + bh_i + bh[j];
    }
    srow[j] = sc;
    __builtin_nontemporal_store(sc, &scores[(size_t)i * L + j]);  // write-once
    lmax = fmaxf(lmax, sc);
  }
  for (int o = 32; o > 0; o >>= 1) lmax = fmaxf(lmax, __shfl_down(lmax, o));
  int wid = tid >> 6, lane = tid & 63;
  if (lane == 0) red[wid] = lmax;
  __syncthreads();
  float rowmax = fmaxf(fmaxf(red[0], red[1]), fmaxf(red[2], red[3]));
  __syncthreads();

  float lsum = 0.0f;
  for (int j = tid; j < L; j += 256) {
    float e = expf((srow[j] - rowmax) * invT);
    srow[j] = e;
    lsum += e;
  }
  for (int o = 32; o > 0; o >>= 1) lsum += __shfl_down(lsum, o);
  if (lane == 0) red[wid] = lsum;
  __syncthreads();
  float total = red[0] + red[1] + red[2] + red[3];
  float inv = 1.0f / total;

  for (int j = tid; j < L; j += 256) {
    float a = srow[j] * inv;
    size_t o = (size_t)i * L + j;
    __builtin_nontemporal_store(a, &A[o]);  // f32 A never re-read on device
    unsigned short h = f2bf(a);
    Ahd[o] = h;                             // re-read by GEMM2 -> keep cached
    Ald[o] = f2bf(a - bf2f(h));
  }
}

// ---------------- counted-vmcnt pipelined bf16 GEMM over virtual K'=3K -----
// C[m][n] = sum over 3 ranges: range 0: Ah·Bh, 1: Ah·Bl, 2: Al·Bh
// A: M x K row-major bf16 (hi/lo), B: N x K row-major bf16 (hi/lo).
// BM=BN=128, BK=64; 256 threads = 4 waves (2M x 2N), per-wave 64x64.
// LDS granule swizzle g^=(row&7): pre-swizzled global source + same XOR on
// the ds_read side (both-sides involution; 2-way banks = free).
// MODE 0: f32 C[m][n] + bias[n], nontemporal. MODE 2: bf16 pair + bias[m] opt.
#define TBM 128
#define TBN 128
#define TBK 64
#define A_USH (TBM * TBK)            // 8192 ushorts = 16KB
#define B_USH (TBN * TBK)            // 8192 ushorts = 16KB
#define BUF_USH (A_USH + B_USH)      // 16384 ushorts = 32KB

template <int MODE>
__global__ __launch_bounds__(256, 2) void gemm_pipe_kernel(
    const unsigned short* __restrict__ Ah, const unsigned short* __restrict__ Al,
    const unsigned short* __restrict__ Bh, const unsigned short* __restrict__ Bl,
    const float* __restrict__ bias, float* __restrict__ C,
    unsigned short* __restrict__ Oh, unsigned short* __restrict__ Ol,
    int M, int N, int K, int TM, int TN) {
  __shared__ unsigned short smem[2][BUF_USH];  // 64KB -> 2 blocks/CU
  const int tid = threadIdx.x;
  const int wave = tid >> 6, lane = tid & 63;
  const int wm = wave >> 1, wn = wave & 1;  // 2 x 2 wave grid
  const int fr = lane & 15, fg = lane >> 4;

  // XCD-chunked bijective block swizzle (grid always a multiple of 8 here)
  int bid = blockIdx.x;
  int chunk = (bid & 7) * (gridDim.x >> 3) + (bid >> 3);
  int bm = chunk / TN, bn = chunk % TN;
  int m0 = bm * TBM, n0 = bn * TBN;

  // ---- staging lane geometry (per-lane global offsets, loop-invariant) ----
  // one wave-load = 64 lanes x 16B = 1KB = 8 rows of 128B; lane (lr,lc):
  const int lr = lane >> 3;                 // row-within-8
  const int lc = lane & 7;                  // dest 16B granule (8 per row)
  const int scol = (lc ^ lr) * 8;           // pre-swizzled source col (ushorts)
  size_t laneA[4], laneB[4];
  int dA[4], dB[4];
#pragma unroll
  for (int i = 0; i < 4; ++i) {
    int arow = wave * 32 + i * 8;           // 4 waves x 4 loads x 8 rows = 128
    laneA[i] = (size_t)(arow + lr) * K + scol;
    dA[i] = arow * TBK;
    laneB[i] = (size_t)(arow + lr) * K + scol;
    dB[i] = A_USH + arow * TBK;
  }

  // ---- ds-read offsets (ushort idx; same XOR as write side) ----
  int aoff[2][4], boff[2][4];
#pragma unroll
  for (int s = 0; s < 2; ++s) {
#pragma unroll
    for (int u = 0; u < 4; ++u) {
      int arow = wm * 64 + u * 16 + fr;     // arow&7 == fr&7
      aoff[s][u] = arow * TBK + (((s * 4 + fg) ^ (fr & 7)) * 8);
      int brow = wn * 64 + u * 16 + fr;
      boff[s][u] = A_USH + brow * TBK + (((s * 4 + fg) ^ (fr & 7)) * 8);
    }
  }

  const int tpr = K >> 6;       // K-tiles per range
  const int NT = 3 * tpr;

  f32x4 acc[4][4];
#pragma unroll
  for (int a = 0; a < 4; ++a)
#pragma unroll
    for (int b = 0; b < 4; ++b) acc[a][b] = (f32x4){0.f, 0.f, 0.f, 0.f};

  auto stage = [&](int t, int buf) {
    int r = (t >= 2 * tpr) ? 2 : ((t >= tpr) ? 1 : 0);
    int koff = (t - r * tpr) << 6;
    const unsigned short* As = (r < 2) ? Ah : Al;
    const unsigned short* Bs = (r == 1) ? Bl : Bh;
    const unsigned short* uA = As + (size_t)m0 * K + koff;
    const unsigned short* uB = Bs + (size_t)n0 * K + koff;
    unsigned short* sb = &smem[buf][0];
#pragma unroll
    for (int i = 0; i < 4; ++i) load_lds16(uA + laneA[i], sb + dA[i]);
#pragma unroll
    for (int i = 0; i < 4; ++i) load_lds16(uB + laneB[i], sb + dB[i]);
  };

  stage(0, 0);  // prologue: 8 loads in flight

  for (int t = 0; t < NT; ++t) {
    const int buf = t & 1;
    if (t + 1 < NT) {
      stage(t + 1, buf ^ 1);                               // +8 -> 16 in flight
      asm volatile("s_waitcnt vmcnt(8)" ::: "memory");     // tile t landed
    } else {
      asm volatile("s_waitcnt vmcnt(0)" ::: "memory");
    }
    __builtin_amdgcn_s_barrier();          // all waves' tile-t data visible
    asm volatile("" ::: "memory");

    const unsigned short* sb = &smem[buf][0];
#pragma unroll
    for (int s = 0; s < 2; ++s) {
      bf16x8 a[4], b[4];
#pragma unroll
      for (int u = 0; u < 4; ++u) a[u] = *(const bf16x8*)&sb[aoff[s][u]];
#pragma unroll
      for (int u = 0; u < 4; ++u) b[u] = *(const bf16x8*)&sb[boff[s][u]];
      __builtin_amdgcn_s_setprio(1);
#pragma unroll
      for (int mt = 0; mt < 4; ++mt)
#pragma unroll
        for (int nt = 0; nt < 4; ++nt)
          acc[mt][nt] = __builtin_amdgcn_mfma_f32_16x16x32_bf16(
              a[mt], b[nt], acc[mt][nt], 0, 0, 0);
      __builtin_amdgcn_s_setprio(0);
    }
    // Guarantee this wave's LDS reads are architecturally complete BEFORE
    // crossing the reuse barrier (independent of where the scheduler places
    // the MFMAs). lgkmcnt is ~0 here in the common schedule -> ~free.
    asm volatile("s_waitcnt lgkmcnt(0)" ::: "memory");
    __builtin_amdgcn_s_barrier();          // reads done -> buffer may be reused
    asm volatile("" ::: "memory");
  }

  // ---- epilogue ----
#pragma unroll
  for (int mt = 0; mt < 4; ++mt) {
#pragma unroll
    for (int nt = 0; nt < 4; ++nt) {
      int row0 = m0 + wm * 64 + mt * 16 + fg * 4;
      int col = n0 + wn * 64 + nt * 16 + fr;
      f32x4 v = acc[mt][nt];
      if (MODE == 0) {
        float bv = bias[col];
#pragma unroll
        for (int j = 0; j < 4; ++j)
          __builtin_nontemporal_store(v[j] + bv, &C[(size_t)(row0 + j) * N + col]);
      } else {
#pragma unroll
        for (int j = 0; j < 4; ++j) {
          float x = v[j] + (bias ? bias[row0 + j] : 0.0f);
          unsigned short h = f2bf(x);
          size_t o = (size_t)(row0 + j) * N + col;
          Oh[o] = h;
          Ol[o] = f2bf(x - bf2f(h));
        }
      }
    }
  }
}

extern "C" void kernel_launch(void* const* d_in, const int* in_sizes, int n_in,
                              void* d_out, int out_size, void* d_ws, size_t ws_size,
                              hipStream_t stream) {
  const float* token_vecs = (const float*)d_in[0];
  const int* pos_idx = (const int*)d_in[1];
  const int* depth = (const int*)d_in[2];
  const int* slot_idx = (const int*)d_in[3];
  const float* token_pos = (const float*)d_in[4];
  const float* conf = (const float*)d_in[5];
  const float* reso = (const float*)d_in[6];
  const float* G_micro = (const float*)d_in[7];
  const float* G_macro = (const float*)d_in[8];
  const float* k_spring = (const float*)d_in[9];
  const float* temperature = (const float*)d_in[10];
  const float* Wv_w = (const float*)d_in[11];
  const float* Wv_b = (const float*)d_in[12];
  const float* Wout_w = (const float*)d_in[13];
  const float* Wout_b = (const float*)d_in[14];

  const int L = in_sizes[1];   // 4096
  const int d = in_sizes[12];  // 2048

  float* out = (float*)d_out;             // L*d
  float* A = out + (size_t)L * d;         // L*L
  float* scores = A + (size_t)L * L;      // L*L

  // workspace layout (~136MB; every buffer fully written before read)
  float* masses = (float*)d_ws;                          // L
  float* bhv = masses + L;                               // L
  float* kpis = bhv + L;                                 // L
  unsigned short* Ahd = (unsigned short*)(kpis + L);     // L*L
  unsigned short* Ald = Ahd + (size_t)L * L;             // L*L
  unsigned short* VTh = Ald + (size_t)L * L;             // d*L (V^T)
  unsigned short* VTl = VTh + (size_t)d * L;             // d*L
  unsigned short* Wh = VTl + (size_t)d * L;              // d*d (Wv then Wout)
  unsigned short* Wl = Wh + (size_t)d * d;               // d*d
  unsigned short* Xh = Wl + (size_t)d * d;               // L*d (reused as AVh)
  unsigned short* Xl = Xh + (size_t)L * d;               // L*d (reused as AVl)
  unsigned short* AVh = Xh;
  unsigned short* AVl = Xl;

  // 1. decompose X + per-token precompute (one pass over X)
  fusedX_kernel<<<L, 256, 0, stream>>>(token_vecs, pos_idx, conf, reso, k_spring,
                                       Xh, Xl, masses, bhv, kpis, L, d);

  // 2. decompose Wv
  decompose_kernel<<<(d * d) / 1024, 256, 0, stream>>>(Wv_w, Wh, Wl, d * d);

  // 3. scores + softmax (writes scores, A, and A bf16 pair)
  scores_softmax_kernel<<<L, 256, L * sizeof(float), stream>>>(
      masses, bhv, kpis, pos_idx, slot_idx, depth, token_pos, conf, G_micro,
      G_macro, temperature, scores, A, Ahd, Ald, L);

  // 4. V^T = Wv · X^T + Wv_b[row]   (M=d, N=L, K=d)
  {
    int TM = d / TBM, TN = L / TBN;  // 16 x 32 = 512 blocks
    gemm_pipe_kernel<2><<<TM * TN, 256, 0, stream>>>(
        Wh, Wl, Xh, Xl, Wv_b, nullptr, VTh, VTl, d, L, d, TM, TN);
  }

  // 5. decompose Wout (reuses Wh/Wl after GEMM1 consumed them)
  decompose_kernel<<<(d * d) / 1024, 256, 0, stream>>>(Wout_w, Wh, Wl, d * d);

  // 6. AV pair = (A @ V) decomposed   (M=L, N=d, K=L; B = V^T)
  {
    int TM = L / TBM, TN = d / TBN;  // 32 x 16 = 512 blocks
    gemm_pipe_kernel<2><<<TM * TN, 256, 0, stream>>>(
        Ahd, Ald, VTh, VTl, nullptr, nullptr, AVh, AVl, L, d, L, TM, TN);
  }

  // 7. out = AV @ Wout^T + Wout_b   (M=L, N=d, K=d)
  {
    int TM = L / TBM, TN = d / TBN;  // 512 blocks
    gemm_pipe_kernel<0><<<TM * TN, 256, 0, stream>>>(
        AVh, AVl, Wh, Wl, Wout_b, out, nullptr, nullptr, L, d, d, TM, TN);
  }
}